// Round 8
// baseline (213.654 us; speedup 1.0000x reference)
//
#include <hip/hip_runtime.h>

#define STEPS 100
#define GCONST 20.0f
#define TSPLIT 8          // time-axis chunks (store-parallelism multiplier)
#define CHUNK 13          // ceil(STEPS/TSPLIT)

typedef float v4f __attribute__((ext_vector_type(4)));

// Time-split streaming scan: blockIdx.y = time-chunk. Each thread owns 4
// simulations (float4, 16B/lane stores matching the proven-fast fill kernel).
// Threads dry-run the recurrence (registers only, op-identical) up to their
// chunk's start step, then store CHUNK steps. 8x thread count -> 7.6
// waves/SIMD of store-issue parallelism; compute is ~5% of the write budget.
__global__ __launch_bounds__(256) void sim_scan_kernel(
    const float* __restrict__ h0,
    const float* __restrict__ pa1,
    const float* __restrict__ pa2,
    const float* __restrict__ pth,
    float* __restrict__ out,
    int n)
{
    const int nv = n >> 2;  // float4 groups
    const int j = blockIdx.x * blockDim.x + threadIdx.x;
    if (j >= nv) return;
    const int c = blockIdx.y;
    const int t0 = c * CHUNK;
    const int t1 = (t0 + CHUNK < STEPS) ? (t0 + CHUNK) : STEPS;
    if (t0 >= STEPS) return;

    const float a1 = *pa1;
    const float a2 = *pa2;
    const float th = *pth;
    const float denom = 1.0f - a1 * (1.0f - th);

    v4f h = reinterpret_cast<const v4f*>(h0)[j];

    // Dry-run (no stores) up to t0 — numerically identical op sequence.
    for (int t = 0; t < t0; ++t) {
        v4f y, yd, cc;
        y.x = (GCONST + a2 * h.x) / denom;
        y.y = (GCONST + a2 * h.y) / denom;
        y.z = (GCONST + a2 * h.z) / denom;
        y.w = (GCONST + a2 * h.w) / denom;
        yd.x = y.x - th * y.x;  yd.y = y.y - th * y.y;
        yd.z = y.z - th * y.z;  yd.w = y.w - th * y.w;
        cc.x = a1 * yd.x + a2 * h.x;  cc.y = a1 * yd.y + a2 * h.y;
        cc.z = a1 * yd.z + a2 * h.z;  cc.w = a1 * yd.w + a2 * h.w;
        h.x = h.x + (yd.x - cc.x);  h.y = h.y + (yd.y - cc.y);
        h.z = h.z + (yd.z - cc.z);  h.w = h.w + (yd.w - cc.w);
    }

    // d_out layout: y_hist [STEPS][n] then h_hist [STEPS][n]
    v4f* oy = reinterpret_cast<v4f*>(out) + (size_t)t0 * nv + j;
    v4f* oh = reinterpret_cast<v4f*>(out + (size_t)STEPS * (size_t)n) + (size_t)t0 * nv + j;

    for (int t = t0; t < t1; ++t) {
        v4f y, yd, cc;
        y.x = (GCONST + a2 * h.x) / denom;
        y.y = (GCONST + a2 * h.y) / denom;
        y.z = (GCONST + a2 * h.z) / denom;
        y.w = (GCONST + a2 * h.w) / denom;
        yd.x = y.x - th * y.x;  yd.y = y.y - th * y.y;
        yd.z = y.z - th * y.z;  yd.w = y.w - th * y.w;
        cc.x = a1 * yd.x + a2 * h.x;  cc.y = a1 * yd.y + a2 * h.y;
        cc.z = a1 * yd.z + a2 * h.z;  cc.w = a1 * yd.w + a2 * h.w;
        h.x = h.x + (yd.x - cc.x);  h.y = h.y + (yd.y - cc.y);
        h.z = h.z + (yd.z - cc.z);  h.w = h.w + (yd.w - cc.w);

        *oy = y;
        *oh = h;
        oy += nv;
        oh += nv;
    }
}

// Scalar tail kernel (full time range) in case n % 4 != 0.
__global__ void sim_scan_tail_kernel(
    const float* __restrict__ h0,
    const float* __restrict__ pa1,
    const float* __restrict__ pa2,
    const float* __restrict__ pth,
    float* __restrict__ out,
    int n, int start)
{
    int i = start + blockIdx.x * blockDim.x + threadIdx.x;
    if (i >= n) return;

    const float a1 = *pa1;
    const float a2 = *pa2;
    const float th = *pth;
    const float denom = 1.0f - a1 * (1.0f - th);

    float h = h0[i];
    float* oy = out + i;
    float* oh = out + (size_t)STEPS * (size_t)n + i;

    for (int t = 0; t < STEPS; ++t) {
        float y = (GCONST + a2 * h) / denom;
        float yd = y - th * y;
        float c = a1 * yd + a2 * h;
        h = h + (yd - c);
        *oy = y;
        *oh = h;
        oy += n;
        oh += n;
    }
}

extern "C" void kernel_launch(void* const* d_in, const int* in_sizes, int n_in,
                              void* d_out, int out_size, void* d_ws, size_t ws_size,
                              hipStream_t stream) {
    const float* h0 = (const float*)d_in[0];
    const float* a1 = (const float*)d_in[1];
    const float* a2 = (const float*)d_in[2];
    const float* th = (const float*)d_in[3];
    float* out = (float*)d_out;

    const int n = in_sizes[0];
    const int nv = n / 4;

    const int block = 256;
    dim3 grid((nv + block - 1) / block, TSPLIT);
    if (nv > 0) {
        sim_scan_kernel<<<grid, block, 0, stream>>>(h0, a1, a2, th, out, n);
    }
    const int rem_start = nv * 4;
    if (rem_start < n) {
        const int rem = n - rem_start;
        sim_scan_tail_kernel<<<(rem + 63) / 64, 64, 0, stream>>>(
            h0, a1, a2, th, out, n, rem_start);
    }
}

// Round 9
// 198.070 us; speedup vs baseline: 1.0787x; 1.0787x over previous
//
#include <hip/hip_runtime.h>

#define STEPS 100
#define GCONST 20.0f

typedef float v4f __attribute__((ext_vector_type(4)));

// Closed-form affine scan: h' = A*h + B  =>  d_t = h_t - h* decays by A each
// step. Per step per elem: y = y* + k*d; d *= A; h = h* + d  (1 mul + 2 FMA,
// serial chain = one 4-cycle mul). Structurally a pure streaming-store loop,
// matching the harness fill kernel that sustains 6.6 TB/s at 3 waves/CU.
__global__ __launch_bounds__(256) void sim_scan_kernel(
    const float* __restrict__ h0,
    const float* __restrict__ pa1,
    const float* __restrict__ pa2,
    const float* __restrict__ pth,
    float* __restrict__ out,
    int n)
{
    const int nv = n >> 2;  // float4 groups
    const int i = blockIdx.x * blockDim.x + threadIdx.x;
    if (i >= nv) return;

    const float a1 = *pa1;
    const float a2 = *pa2;
    const float th = *pth;
    const float denom = 1.0f - a1 * (1.0f - th);   // 0.49
    const float w    = (1.0f - a1) * (1.0f - th);  // 0.34
    const float A    = (1.0f - a2) + w * a2 / denom;
    const float B    = w * GCONST / denom;
    const float hs   = B / (1.0f - A);             // fixed point of h
    const float ys   = (GCONST + a2 * hs) / denom; // fixed point of y
    const float k    = a2 / denom;

    v4f hv = reinterpret_cast<const v4f*>(h0)[i];
    v4f d;
    d.x = hv.x - hs;  d.y = hv.y - hs;
    d.z = hv.z - hs;  d.w = hv.w - hs;

    // d_out layout: y_hist [STEPS][n] then h_hist [STEPS][n]
    v4f* oy = reinterpret_cast<v4f*>(out) + i;
    v4f* oh = reinterpret_cast<v4f*>(out + (size_t)STEPS * (size_t)n) + i;

    #pragma unroll 4
    for (int t = 0; t < STEPS; ++t) {
        v4f y, h;
        // y_t uses pre-update d (= h_{t-1} - h*)
        y.x = ys + k * d.x;  y.y = ys + k * d.y;
        y.z = ys + k * d.z;  y.w = ys + k * d.w;
        d.x *= A;  d.y *= A;  d.z *= A;  d.w *= A;
        h.x = hs + d.x;  h.y = hs + d.y;
        h.z = hs + d.z;  h.w = hs + d.w;

        *oy = y;
        *oh = h;
        oy += nv;
        oh += nv;
    }
}

// Scalar tail (n % 4 != 0; unused for n=250000 but safe).
__global__ void sim_scan_tail_kernel(
    const float* __restrict__ h0,
    const float* __restrict__ pa1,
    const float* __restrict__ pa2,
    const float* __restrict__ pth,
    float* __restrict__ out,
    int n, int start)
{
    int i = start + blockIdx.x * blockDim.x + threadIdx.x;
    if (i >= n) return;

    const float a1 = *pa1;
    const float a2 = *pa2;
    const float th = *pth;
    const float denom = 1.0f - a1 * (1.0f - th);
    const float w    = (1.0f - a1) * (1.0f - th);
    const float A    = (1.0f - a2) + w * a2 / denom;
    const float B    = w * GCONST / denom;
    const float hs   = B / (1.0f - A);
    const float ys   = (GCONST + a2 * hs) / denom;
    const float k    = a2 / denom;

    float d = h0[i] - hs;
    float* oy = out + i;
    float* oh = out + (size_t)STEPS * (size_t)n + i;

    for (int t = 0; t < STEPS; ++t) {
        float y = ys + k * d;
        d *= A;
        float h = hs + d;
        *oy = y;
        *oh = h;
        oy += n;
        oh += n;
    }
}

extern "C" void kernel_launch(void* const* d_in, const int* in_sizes, int n_in,
                              void* d_out, int out_size, void* d_ws, size_t ws_size,
                              hipStream_t stream) {
    const float* h0 = (const float*)d_in[0];
    const float* a1 = (const float*)d_in[1];
    const float* a2 = (const float*)d_in[2];
    const float* th = (const float*)d_in[3];
    float* out = (float*)d_out;

    const int n = in_sizes[0];
    const int nv = n / 4;

    const int block = 256;
    const int grid = (nv + block - 1) / block;
    if (nv > 0) {
        sim_scan_kernel<<<grid, block, 0, stream>>>(h0, a1, a2, th, out, n);
    }
    const int rem_start = nv * 4;
    if (rem_start < n) {
        const int rem = n - rem_start;
        sim_scan_tail_kernel<<<(rem + 63) / 64, 64, 0, stream>>>(
            h0, a1, a2, th, out, n, rem_start);
    }
}